// Round 14
// baseline (409.645 us; speedup 1.0000x reference)
//
#include <hip/hip_runtime.h>

// HeteroGraphAttentionLayer: B=8, S=2048, E=1024, H=4, D=256
// single cast launch | GEMM1 | per-head QKV (V tiled+phi, Q pre-scaled) |
// flash attention v14: v6 skeleton (grid 32x32, 64KB LDS, 2 blocks/CU,
//   8 waves/CU) + kv-split register blocking: wave (qh,h2) owns 32 q-rows x
//   32-kv half; every K/V fragment feeds 2 MFMAs (LDS reads halved);
//   2-pass end-of-kernel softmax merge through LDS |
// per-head out_proj -> fp32 d_out.

typedef unsigned short u16;
typedef short s8v __attribute__((ext_vector_type(8)));   // 8 x bf16
typedef float f4v __attribute__((ext_vector_type(4)));   // mfma accum
typedef unsigned short us8v __attribute__((ext_vector_type(8)));

typedef const __attribute__((address_space(1))) void* gas_t;
typedef __attribute__((address_space(3))) void* las_t;

#define QSCALE 0.09016844f   // (1/sqrt(256)) * log2(e): softmax in exp2 domain

__device__ __forceinline__ u16 f2bf(float f) {
  unsigned u = __builtin_bit_cast(unsigned, f);
  unsigned r = u + 0x7FFFu + ((u >> 16) & 1u);   // RNE
  return (u16)(r >> 16);
}

// packed f32x2 -> bf16x2 (low = a, high = b), RNE on gfx950
__device__ __forceinline__ unsigned cvtpk(float a, float b) {
  unsigned r;
  asm("v_cvt_pk_bf16_f32 %0, %1, %2" : "=v"(r) : "v"(a), "v"(b));
  return r;
}

__device__ __forceinline__ void gload16(const void* g, void* l) {
  __builtin_amdgcn_global_load_lds((gas_t)g, (las_t)l, 16, 0, 0);
}

// One launch casts everything: x (4194304 float4) | W_lin (262144) |
// W_in (196608, QSCALE on q rows) | W_out (65536). 18432 blocks x 256.
__global__ void cast_all(const float* __restrict__ x, const float* __restrict__ Wl,
                         const float* __restrict__ Wi, const float* __restrict__ Wo,
                         u16* __restrict__ xb, u16* __restrict__ WLb,
                         u16* __restrict__ WIb, u16* __restrict__ WOb) {
  const int i = blockIdx.x * blockDim.x + threadIdx.x;   // 0..4718591
  const float* src;
  u16* dst;
  int j;
  float sc = 1.0f;
  if (i < 4194304) {
    src = x; dst = xb; j = i;
  } else {
    const int k = i - 4194304;
    if (k < 262144) {
      src = Wl; dst = WLb; j = k;
    } else if (k < 458752) {
      src = Wi; dst = WIb; j = k - 262144;
      if (((j >> 6) % 768) < 256) sc = QSCALE;   // q rows of W_in
    } else {
      src = Wo; dst = WOb; j = k - 458752;
    }
  }
  const float4 v = reinterpret_cast<const float4*>(src)[j];
  ushort4 o;
  o.x = f2bf(v.x * sc); o.y = f2bf(v.y * sc); o.z = f2bf(v.z * sc); o.w = f2bf(v.w * sc);
  reinterpret_cast<ushort4*>(dst)[j] = o;
}

// ---------------------------------------------------------------------------
// Generic 128x128-tile bf16 NT-GEMM: C = A(MxK) * B(NxK)^T + bias
// MODE 0: GEMM1 (K=1024) -> bf16 | MODE 1: QKV (K=256/head) | MODE 2: out_proj
// MODE 1 V output: tiled [bh][s_tile 32][d 256][kv 64] with phi-permuted kv
// slots: slot k holds kv = 32*(k>>5) + 16*((k&7)>>2) + 4*((k>>3)&3) + (k&3).
// ---------------------------------------------------------------------------
template <int MODE>
__global__ void __launch_bounds__(256, 2) gemm128(
    const u16* __restrict__ A, const u16* __restrict__ Bw,
    const float* __restrict__ bias,
    u16* __restrict__ outB, float* __restrict__ outF,
    u16* __restrict__ Qo, u16* __restrict__ Ko, u16* __restrict__ Vo)
{
  constexpr int K    = (MODE == 0) ? 1024 : 256;
  constexpr int LDA  = 1024;
  constexpr int LDB  = (MODE == 0) ? 1024 : 256;
  constexpr int SMEM = (MODE == 1) ? 35072 : 32768;

  const int bx = blockIdx.x, ny = blockIdx.y, h = blockIdx.z;
  const int tid = threadIdx.x;
  const int wid = tid >> 6, l = tid & 63;
  const int l15 = l & 15, lg = l >> 4;
  const int wr = wid >> 1, wc = wid & 1;

  __shared__ __align__(16) char smem[SMEM];
  char* Al = smem;
  char* Bl = smem + 16384;

  const u16* Abase = A + (size_t)bx * 128 * LDA + ((MODE == 0) ? 0 : h * 256);
  const size_t bwoff = (MODE == 0) ? 0
                      : ((MODE == 1) ? (size_t)h * 768 * 256 : (size_t)h * 256 * 256);
  const u16* Bbase = Bw + bwoff + (size_t)ny * 128 * LDB;

  f4v acc[4][4];
#pragma unroll
  for (int i = 0; i < 4; ++i)
#pragma unroll
    for (int j = 0; j < 4; ++j) acc[i][j] = f4v{0.f, 0.f, 0.f, 0.f};

  for (int k0 = 0; k0 < K; k0 += 64) {
    __syncthreads();
#pragma unroll
    for (int ii = 0; ii < 4; ++ii) {
      const int i = wid * 4 + ii;
      const int row = i * 8 + (l >> 3);
      const int c = l & 7;
      gload16(Abase + (size_t)row * LDA + k0 + ((c ^ (row & 7)) << 3), Al + i * 1024);
    }
#pragma unroll
    for (int ii = 0; ii < 4; ++ii) {
      const int i = wid * 4 + ii;
      const int row = i * 8 + (l >> 3);
      const int c = l & 7;
      gload16(Bbase + (size_t)row * LDB + k0 + ((c ^ (row & 7)) << 3), Bl + i * 1024);
    }
    __syncthreads();
#pragma unroll
    for (int kf = 0; kf < 2; ++kf) {
      s8v a[4];
#pragma unroll
      for (int mf = 0; mf < 4; ++mf) {
        const int row = wr * 64 + mf * 16 + l15;
        a[mf] = *reinterpret_cast<const s8v*>(
            Al + row * 128 + (((kf * 32 + lg * 8) << 1) ^ ((row & 7) << 4)));
      }
#pragma unroll
      for (int nf = 0; nf < 4; ++nf) {
        const int n = wc * 64 + nf * 16 + l15;
        const s8v b = *reinterpret_cast<const s8v*>(
            Bl + n * 128 + (((kf * 32 + lg * 8) << 1) ^ ((n & 7) << 4)));
#pragma unroll
        for (int mf = 0; mf < 4; ++mf)
          acc[mf][nf] = __builtin_amdgcn_mfma_f32_16x16x32_bf16(a[mf], b, acc[mf][nf], 0, 0, 0);
      }
    }
  }

  const int mbase = bx * 128 + wr * 64;
  const int nbase = ny * 128 + wc * 64;

  if constexpr (MODE == 0) {
#pragma unroll
    for (int nf = 0; nf < 4; ++nf) {
      const int colg = nbase + nf * 16 + l15;
      const float bv = bias[colg];
#pragma unroll
      for (int mf = 0; mf < 4; ++mf)
#pragma unroll
        for (int r = 0; r < 4; ++r) {
          const int mr = mbase + mf * 16 + lg * 4 + r;
          outB[(size_t)mr * 1024 + colg] = f2bf(acc[mf][nf][r] + bv);
        }
    }
  } else if constexpr (MODE == 2) {
#pragma unroll
    for (int nf = 0; nf < 4; ++nf) {
      const int colg = nbase + nf * 16 + l15;
      const float bv = bias[h * 256 + colg];
#pragma unroll
      for (int mf = 0; mf < 4; ++mf)
#pragma unroll
        for (int r = 0; r < 4; ++r) {
          const int mr = mbase + mf * 16 + lg * 4 + r;
          outF[(size_t)mr * 1024 + h * 256 + colg] = acc[mf][nf][r] + bv;
        }
    }
  } else {  // MODE 1: QKV
    if (ny < 4) {                                // Q (ny 0,1) / K (ny 2,3)
      u16* dst = (ny < 2) ? Qo : Ko;
      const int cb = (ny < 2) ? 0 : 256;
#pragma unroll
      for (int nf = 0; nf < 4; ++nf) {
        const int colg = nbase + nf * 16 + l15;
        const float bscale = (ny < 2) ? QSCALE : 1.0f;   // Q bias pre-scaled
        const float bv = bias[h * 768 + colg] * bscale;
        const int d = colg - cb;
#pragma unroll
        for (int mf = 0; mf < 4; ++mf)
#pragma unroll
          for (int r = 0; r < 4; ++r) {
            const int mr = mbase + mf * 16 + lg * 4 + r;
            const int b = mr >> 11, s = mr & 2047;
            dst[((size_t)(b * 4 + h) * 2048 + s) * 256 + d] = f2bf(acc[mf][nf][r] + bv);
          }
      }
    } else {                                     // V (ny 4,5): transpose via LDS
      __syncthreads();
      short* tr = reinterpret_cast<short*>(smem);
#pragma unroll
      for (int nf = 0; nf < 4; ++nf) {
        const int colg = nbase + nf * 16 + l15;
        const float bv = bias[h * 768 + colg];
        const int cl = wc * 64 + nf * 16 + l15;
#pragma unroll
        for (int mf = 0; mf < 4; ++mf)
#pragma unroll
          for (int r = 0; r < 4; ++r) {
            const int rl = wr * 64 + mf * 16 + lg * 4 + r;
            tr[rl * 137 + cl] = (short)f2bf(acc[mf][nf][r] + bv);
          }
      }
      __syncthreads();
      const int b = bx >> 4;
#pragma unroll
      for (int rep = 0; rep < 8; ++rep) {
        const int u = rep * 256 + tid;
        const int d = u >> 4, sb = u & 15;       // d: local col 0..127, sb: 8-run idx
        const int dglob = (ny - 4) * 128 + d;
        const int tile = (bx & 15) * 2 + (sb >> 3);
        const int c = sb & 7;                    // kv chunk within 64-tile
        // phi^-1: kv run c*8..c*8+3 -> slot kA..kA+3 ; c*8+4..7 -> kA+8..+11
        const int kA = 32 * (c >> 2) + 8 * ((2 * c) & 3) + 4 * ((c >> 1) & 1);
        u16* base = Vo + (((size_t)(b * 4 + h) * 32 + tile) * 256 + dglob) * 64;
        ushort4 lo, hi;
        lo.x = (u16)tr[(sb * 8 + 0) * 137 + d];
        lo.y = (u16)tr[(sb * 8 + 1) * 137 + d];
        lo.z = (u16)tr[(sb * 8 + 2) * 137 + d];
        lo.w = (u16)tr[(sb * 8 + 3) * 137 + d];
        hi.x = (u16)tr[(sb * 8 + 4) * 137 + d];
        hi.y = (u16)tr[(sb * 8 + 5) * 137 + d];
        hi.z = (u16)tr[(sb * 8 + 6) * 137 + d];
        hi.w = (u16)tr[(sb * 8 + 7) * 137 + d];
        *reinterpret_cast<ushort4*>(base + kA)     = lo;
        *reinterpret_cast<ushort4*>(base + kA + 8) = hi;
      }
    }
  }
}

// ---------------------------------------------------------------------------
// Flash attention v14. Grid (32,32): qt, bh — 1024 blocks, 64KB LDS,
// 2 blocks/CU, 8 waves/CU. Wave wid: qh=wid&1 (32 q-rows), h2=wid>>1
// (32-kv half). Swapped QK^T with mf=2 q-frags: each kb/vb fragment feeds
// 2 MFMAs -> 32 LDS reads/wave/tile (half of v6). Per-half online softmax;
// in-register P; 2-pass merge of kv-halves through LDS at the end.
// ---------------------------------------------------------------------------
__global__ void __launch_bounds__(256, 2) attn_fwd(
    const u16* __restrict__ Q, const u16* __restrict__ Kk,
    const u16* __restrict__ Vt, u16* __restrict__ AO)
{
  const int qt = blockIdx.x;                     // 0..31
  const int bh = blockIdx.y;                     // 0..31
  const int tid = threadIdx.x;
  const int wid = tid >> 6, l = tid & 63;
  const int l15 = l & 15, lg = l >> 4;
  const int qh = wid & 1;                        // q-half of the 64-row block
  const int h2 = wid >> 1;                       // kv-half of each 64-kv tile

  __shared__ __align__(16) char smem[65536];
  char* Kl = smem;
  char* Vl = smem + 32768;

  const size_t kbase = (size_t)bh * 2048 * 256;

  // Q fragments: 32 rows/wave = 2 frags (pre-scaled by log2e/16 upstream)
  s8v qa[2][8];
#pragma unroll
  for (int mf = 0; mf < 2; ++mf) {
    const u16* qrow = Q + ((size_t)bh * 2048 + qt * 64 + qh * 32 + mf * 16 + l15) * 256;
#pragma unroll
    for (int kf = 0; kf < 8; ++kf)
      qa[mf][kf] = *reinterpret_cast<const s8v*>(qrow + kf * 32 + lg * 8);
  }

  f4v O[2][16];
#pragma unroll
  for (int mf = 0; mf < 2; ++mf)
#pragma unroll
    for (int df = 0; df < 16; ++df) O[mf][df] = f4v{0.f, 0.f, 0.f, 0.f};
  float m_run[2] = {-1e30f, -1e30f}, l_run[2] = {0.f, 0.f};   // per-lane, q=l15

  for (int t0 = 0; t0 < 2048; t0 += 64) {
    __syncthreads();                              // prev tile's LDS reads done
#pragma unroll
    for (int ii = 0; ii < 8; ++ii) {              // K tile 64x256 (rows 512B)
      const int i = wid * 8 + ii;
      const int row = i * 2 + (l >> 5);
      const int c = l & 31;
      gload16(Kk + kbase + (size_t)(t0 + row) * 256 + ((c ^ (row & 7)) << 3), Kl + i * 1024);
    }
    {
      const u16* vtile = Vt + ((size_t)bh * 32 + (t0 >> 6)) * 16384;  // [256][64]
#pragma unroll
      for (int ii = 0; ii < 8; ++ii) {            // V tile (contiguous 32KB)
        const int i = wid * 8 + ii;
        const int d = i * 8 + (l >> 3);
        const int c = l & 7;
        gload16(vtile + (size_t)d * 64 + ((c ^ (d & 7)) << 3), Vl + i * 1024);
      }
    }
    __syncthreads();                              // staged tile visible

    // QK^T swapped, this wave's kv-half: Sx[mf][nf] reg r =
    //   S[kv = h2*32 + nf*16 + lg*4 + r][q = qh*32 + mf*16 + l15]
    f4v Sx[2][2];
#pragma unroll
    for (int mf = 0; mf < 2; ++mf)
#pragma unroll
      for (int nf = 0; nf < 2; ++nf) Sx[mf][nf] = f4v{0.f, 0.f, 0.f, 0.f};
#pragma unroll
    for (int kf = 0; kf < 8; ++kf) {
      const int ch = kf * 4 + lg;
#pragma unroll
      for (int nf = 0; nf < 2; ++nf) {
        const int tl = h2 * 32 + nf * 16 + l15;
        const s8v kb = *reinterpret_cast<const s8v*>(
            Kl + tl * 512 + ((ch ^ (tl & 7)) << 4));
        Sx[0][nf] = __builtin_amdgcn_mfma_f32_16x16x32_bf16(kb, qa[0][kf], Sx[0][nf], 0, 0, 0);
        Sx[1][nf] = __builtin_amdgcn_mfma_f32_16x16x32_bf16(kb, qa[1][kf], Sx[1][nf], 0, 0, 0);
      }
    }

    // per-half online softmax + in-register P pack (phi baked into V layout)
    s8v pa[2];
#pragma unroll
    for (int mf = 0; mf < 2; ++mf) {
      float mloc = fmaxf(fmaxf(fmaxf(Sx[mf][0][0], Sx[mf][0][1]),
                               fmaxf(Sx[mf][0][2], Sx[mf][0][3])),
                         fmaxf(fmaxf(Sx[mf][1][0], Sx[mf][1][1]),
                               fmaxf(Sx[mf][1][2], Sx[mf][1][3])));
      mloc = fmaxf(mloc, __shfl_xor(mloc, 16));
      mloc = fmaxf(mloc, __shfl_xor(mloc, 32));

      if (__any(mloc > m_run[mf] + 11.5f)) {      // defer-max (exp2 domain)
        const float mn = fmaxf(m_run[mf], mloc);
        const float fac = __builtin_exp2f(m_run[mf] - mn);
        m_run[mf] = mn;
        l_run[mf] *= fac;
        float facr[4];
#pragma unroll
        for (int r = 0; r < 4; ++r) facr[r] = __shfl(fac, lg * 4 + r);
#pragma unroll
        for (int df = 0; df < 16; ++df) {
          O[mf][df][0] *= facr[0]; O[mf][df][1] *= facr[1];
          O[mf][df][2] *= facr[2]; O[mf][df][3] *= facr[3];
        }
      }

      float sum = 0.f;
#pragma unroll
      for (int nf = 0; nf < 2; ++nf)
#pragma unroll
        for (int r = 0; r < 4; ++r) {
          Sx[mf][nf][r] = __builtin_exp2f(Sx[mf][nf][r] - m_run[mf]);
          sum += Sx[mf][nf][r];
        }
      sum += __shfl_xor(sum, 16);
      sum += __shfl_xor(sum, 32);
      l_run[mf] += sum;

      int4 w;
      w.x = (int)cvtpk(Sx[mf][0][0], Sx[mf][0][1]);
      w.y = (int)cvtpk(Sx[mf][0][2], Sx[mf][0][3]);
      w.z = (int)cvtpk(Sx[mf][1][0], Sx[mf][1][1]);
      w.w = (int)cvtpk(Sx[mf][1][2], Sx[mf][1][3]);
      pa[mf] = __builtin_bit_cast(s8v, w);
    }

    // PV over this kv-half: each vb feeds both q-frags
    {
      const int ch = h2 * 4 + lg;
#pragma unroll
      for (int df = 0; df < 16; ++df) {
        const int dl = df * 16 + l15;
        const s8v vb = *reinterpret_cast<const s8v*>(
            Vl + dl * 128 + ((ch ^ (dl & 7)) << 4));
        O[0][df] = __builtin_amdgcn_mfma_f32_16x16x32_bf16(pa[0], vb, O[0][df], 0, 0, 0);
        O[1][df] = __builtin_amdgcn_mfma_f32_16x16x32_bf16(pa[1], vb, O[1][df], 0, 0, 0);
      }
    }
  }

  // -------- merge kv-halves (2 passes, 32KB LDS each) and store --------
  __syncthreads();                                // all waves done with K/V LDS
  float* mlbuf = reinterpret_cast<float*>(smem);          // [2 arrays][qh*2+mf][16]
  float* Obuf  = reinterpret_cast<float*>(smem + 1024);   // per pass: [qh][16][256]

  if (h2 == 1 && lg == 0) {
    mlbuf[(qh * 2 + 0) * 16 + l15] = m_run[0];
    mlbuf[(qh * 2 + 1) * 16 + l15] = m_run[1];
    mlbuf[64 + (qh * 2 + 0) * 16 + l15] = l_run[0];
    mlbuf[64 + (qh * 2 + 1) * 16 + l15] = l_run[1];
  }

  const int b = bh >> 2, h = bh & 3;
#pragma unroll
  for (int mf = 0; mf < 2; ++mf) {
    __syncthreads();
    if (h2 == 1) {                                // publish this half's O[mf]
      float* ob = Obuf + qh * 4096;
#pragma unroll
      for (int df = 0; df < 16; ++df)
#pragma unroll
        for (int r = 0; r < 4; ++r)
          ob[(lg * 4 + r) * 256 + df * 16 + l15] = O[mf][df][r];
    }
    __syncthreads();
    if (h2 == 0) {                                // merge + normalize + store
      const float m0 = m_run[mf];
      const float m1 = mlbuf[(qh * 2 + mf) * 16 + l15];
      const float l1 = mlbuf[64 + (qh * 2 + mf) * 16 + l15];
      const float mn = fmaxf(m0, m1);
      const float f0 = __builtin_exp2f(m0 - mn);
      const float f1 = __builtin_exp2f(m1 - mn);
      const float inv = 1.0f / (l_run[mf] * f0 + l1 * f1);
      float f0r[4], f1r[4];
#pragma unroll
      for (int r = 0; r < 4; ++r) {
        f0r[r] = __shfl(f0 * inv, lg * 4 + r);
        f1r[r] = __shfl(f1 * inv, lg * 4 + r);
      }
      const float* ob = Obuf + qh * 4096;
#pragma unroll
      for (int df = 0; df < 16; ++df)
#pragma unroll
        for (int r = 0; r < 4; ++r) {
          const float v = O[mf][df][r] * f0r[r]
                        + ob[(lg * 4 + r) * 256 + df * 16 + l15] * f1r[r];
          const int srow = qt * 64 + qh * 32 + mf * 16 + lg * 4 + r;
          AO[(size_t)(b * 2048 + srow) * 1024 + h * 256 + df * 16 + l15] = f2bf(v);
        }
    }
  }
}

// ---------------------------------------------------------------------------
extern "C" void kernel_launch(void* const* d_in, const int* in_sizes, int n_in,
                              void* d_out, int out_size, void* d_ws, size_t ws_size,
                              hipStream_t stream) {
  (void)in_sizes; (void)n_in; (void)out_size; (void)ws_size;
  const float* x     = (const float*)d_in[0];
  const float* W_lin = (const float*)d_in[1];
  const float* b_lin = (const float*)d_in[2];
  const float* W_in  = (const float*)d_in[3];
  const float* b_in  = (const float*)d_in[4];
  const float* W_out = (const float*)d_in[5];
  const float* b_out = (const float*)d_in[6];

  char* ws = (char*)d_ws;
  u16* Qb  = (u16*)(ws);                               // 32 MB [B,H,S,D]
  u16* Vtb = (u16*)(ws + (32ull << 20));               // 32 MB [B,H,32,256,64] tiled
  u16* AOb = (u16*)(ws + (64ull << 20));               // 32 MB [B,S,E]
  u16* WLb = (u16*)(ws + (96ull << 20));               // 2 MB
  u16* WIb = (u16*)(ws + (98ull << 20));               // 1.5 MB
  u16* WOb = (u16*)(ws + (98ull << 20) + 1572864ull);  // 0.5 MB

  char* doc  = (char*)d_out;
  u16* xb    = (u16*)doc;                    // 32 MB, dead after gemm<0>
  u16* xproj = (u16*)(doc + (32ull << 20));  // 32 MB, dead after gemm<1>
  u16* Kb    = (u16*)doc;                    // K reuses xb region [B,H,S,D]
  float* outF = (float*)d_out;

  cast_all<<<18432, 256, 0, stream>>>(x, W_lin, W_in, W_out, xb, WLb, WIb, WOb);

  gemm128<0><<<dim3(128, 8, 1), 256, 0, stream>>>(xb, WLb, b_lin, xproj, nullptr,
                                                  nullptr, nullptr, nullptr);
  gemm128<1><<<dim3(128, 6, 4), 256, 0, stream>>>(xproj, WIb, b_in, nullptr, nullptr,
                                                  Qb, Kb, Vtb);
  attn_fwd<<<dim3(32, 32, 1), 256, 0, stream>>>(Qb, Kb, Vtb, AOb);
  gemm128<2><<<dim3(128, 2, 4), 256, 0, stream>>>(AOb, WOb, b_out, nullptr, outF,
                                                  nullptr, nullptr, nullptr);
}

// Round 15
// 325.464 us; speedup vs baseline: 1.2586x; 1.2586x over previous
//
#include <hip/hip_runtime.h>

// HeteroGraphAttentionLayer: B=8, S=2048, E=1024, H=4, D=256
// single cast launch (x + all weights) | GEMM1 | per-head QKV (V tiled+phi,
// Q pre-scaled log2e/16) | flash attention v6 (grid 32x32, 4 waves x 16 rows,
// KVBLK=64, 2-barrier loop, swapped QK^T, in-lane softmax, in-register P) |
// per-head out_proj -> fp32 d_out.   [v15 = v13 restored: best-known state]

typedef unsigned short u16;
typedef short s8v __attribute__((ext_vector_type(8)));   // 8 x bf16
typedef float f4v __attribute__((ext_vector_type(4)));   // mfma accum
typedef unsigned short us8v __attribute__((ext_vector_type(8)));

typedef const __attribute__((address_space(1))) void* gas_t;
typedef __attribute__((address_space(3))) void* las_t;

#define QSCALE 0.09016844f   // (1/sqrt(256)) * log2(e): softmax in exp2 domain

__device__ __forceinline__ u16 f2bf(float f) {
  unsigned u = __builtin_bit_cast(unsigned, f);
  unsigned r = u + 0x7FFFu + ((u >> 16) & 1u);   // RNE
  return (u16)(r >> 16);
}

// packed f32x2 -> bf16x2 (low = a, high = b), RNE on gfx950
__device__ __forceinline__ unsigned cvtpk(float a, float b) {
  unsigned r;
  asm("v_cvt_pk_bf16_f32 %0, %1, %2" : "=v"(r) : "v"(a), "v"(b));
  return r;
}

__device__ __forceinline__ void gload16(const void* g, void* l) {
  __builtin_amdgcn_global_load_lds((gas_t)g, (las_t)l, 16, 0, 0);
}

// One launch casts everything: x (4194304 float4) | W_lin (262144) |
// W_in (196608, QSCALE on q rows) | W_out (65536). 18432 blocks x 256.
__global__ void cast_all(const float* __restrict__ x, const float* __restrict__ Wl,
                         const float* __restrict__ Wi, const float* __restrict__ Wo,
                         u16* __restrict__ xb, u16* __restrict__ WLb,
                         u16* __restrict__ WIb, u16* __restrict__ WOb) {
  const int i = blockIdx.x * blockDim.x + threadIdx.x;   // 0..4718591
  const float* src;
  u16* dst;
  int j;
  float sc = 1.0f;
  if (i < 4194304) {
    src = x; dst = xb; j = i;
  } else {
    const int k = i - 4194304;
    if (k < 262144) {
      src = Wl; dst = WLb; j = k;
    } else if (k < 458752) {
      src = Wi; dst = WIb; j = k - 262144;
      if (((j >> 6) % 768) < 256) sc = QSCALE;   // q rows of W_in
    } else {
      src = Wo; dst = WOb; j = k - 458752;
    }
  }
  const float4 v = reinterpret_cast<const float4*>(src)[j];
  ushort4 o;
  o.x = f2bf(v.x * sc); o.y = f2bf(v.y * sc); o.z = f2bf(v.z * sc); o.w = f2bf(v.w * sc);
  reinterpret_cast<ushort4*>(dst)[j] = o;
}

// ---------------------------------------------------------------------------
// Generic 128x128-tile bf16 NT-GEMM: C = A(MxK) * B(NxK)^T + bias
// MODE 0: GEMM1 (K=1024) -> bf16 | MODE 1: QKV (K=256/head) | MODE 2: out_proj
// MODE 1 V output: tiled [bh][s_tile 32][d 256][kv 64] with phi-permuted kv
// slots: slot k holds kv = 32*(k>>5) + 16*((k&7)>>2) + 4*((k>>3)&3) + (k&3).
// ---------------------------------------------------------------------------
template <int MODE>
__global__ void __launch_bounds__(256, 2) gemm128(
    const u16* __restrict__ A, const u16* __restrict__ Bw,
    const float* __restrict__ bias,
    u16* __restrict__ outB, float* __restrict__ outF,
    u16* __restrict__ Qo, u16* __restrict__ Ko, u16* __restrict__ Vo)
{
  constexpr int K    = (MODE == 0) ? 1024 : 256;
  constexpr int LDA  = 1024;
  constexpr int LDB  = (MODE == 0) ? 1024 : 256;
  constexpr int SMEM = (MODE == 1) ? 35072 : 32768;

  const int bx = blockIdx.x, ny = blockIdx.y, h = blockIdx.z;
  const int tid = threadIdx.x;
  const int wid = tid >> 6, l = tid & 63;
  const int l15 = l & 15, lg = l >> 4;
  const int wr = wid >> 1, wc = wid & 1;

  __shared__ __align__(16) char smem[SMEM];
  char* Al = smem;
  char* Bl = smem + 16384;

  const u16* Abase = A + (size_t)bx * 128 * LDA + ((MODE == 0) ? 0 : h * 256);
  const size_t bwoff = (MODE == 0) ? 0
                      : ((MODE == 1) ? (size_t)h * 768 * 256 : (size_t)h * 256 * 256);
  const u16* Bbase = Bw + bwoff + (size_t)ny * 128 * LDB;

  f4v acc[4][4];
#pragma unroll
  for (int i = 0; i < 4; ++i)
#pragma unroll
    for (int j = 0; j < 4; ++j) acc[i][j] = f4v{0.f, 0.f, 0.f, 0.f};

  for (int k0 = 0; k0 < K; k0 += 64) {
    __syncthreads();
#pragma unroll
    for (int ii = 0; ii < 4; ++ii) {
      const int i = wid * 4 + ii;
      const int row = i * 8 + (l >> 3);
      const int c = l & 7;
      gload16(Abase + (size_t)row * LDA + k0 + ((c ^ (row & 7)) << 3), Al + i * 1024);
    }
#pragma unroll
    for (int ii = 0; ii < 4; ++ii) {
      const int i = wid * 4 + ii;
      const int row = i * 8 + (l >> 3);
      const int c = l & 7;
      gload16(Bbase + (size_t)row * LDB + k0 + ((c ^ (row & 7)) << 3), Bl + i * 1024);
    }
    __syncthreads();
#pragma unroll
    for (int kf = 0; kf < 2; ++kf) {
      s8v a[4];
#pragma unroll
      for (int mf = 0; mf < 4; ++mf) {
        const int row = wr * 64 + mf * 16 + l15;
        a[mf] = *reinterpret_cast<const s8v*>(
            Al + row * 128 + (((kf * 32 + lg * 8) << 1) ^ ((row & 7) << 4)));
      }
#pragma unroll
      for (int nf = 0; nf < 4; ++nf) {
        const int n = wc * 64 + nf * 16 + l15;
        const s8v b = *reinterpret_cast<const s8v*>(
            Bl + n * 128 + (((kf * 32 + lg * 8) << 1) ^ ((n & 7) << 4)));
#pragma unroll
        for (int mf = 0; mf < 4; ++mf)
          acc[mf][nf] = __builtin_amdgcn_mfma_f32_16x16x32_bf16(a[mf], b, acc[mf][nf], 0, 0, 0);
      }
    }
  }

  const int mbase = bx * 128 + wr * 64;
  const int nbase = ny * 128 + wc * 64;

  if constexpr (MODE == 0) {
#pragma unroll
    for (int nf = 0; nf < 4; ++nf) {
      const int colg = nbase + nf * 16 + l15;
      const float bv = bias[colg];
#pragma unroll
      for (int mf = 0; mf < 4; ++mf)
#pragma unroll
        for (int r = 0; r < 4; ++r) {
          const int mr = mbase + mf * 16 + lg * 4 + r;
          outB[(size_t)mr * 1024 + colg] = f2bf(acc[mf][nf][r] + bv);
        }
    }
  } else if constexpr (MODE == 2) {
#pragma unroll
    for (int nf = 0; nf < 4; ++nf) {
      const int colg = nbase + nf * 16 + l15;
      const float bv = bias[h * 256 + colg];
#pragma unroll
      for (int mf = 0; mf < 4; ++mf)
#pragma unroll
        for (int r = 0; r < 4; ++r) {
          const int mr = mbase + mf * 16 + lg * 4 + r;
          outF[(size_t)mr * 1024 + h * 256 + colg] = acc[mf][nf][r] + bv;
        }
    }
  } else {  // MODE 1: QKV
    if (ny < 4) {                                // Q (ny 0,1) / K (ny 2,3)
      u16* dst = (ny < 2) ? Qo : Ko;
      const int cb = (ny < 2) ? 0 : 256;
#pragma unroll
      for (int nf = 0; nf < 4; ++nf) {
        const int colg = nbase + nf * 16 + l15;
        const float bscale = (ny < 2) ? QSCALE : 1.0f;   // Q bias pre-scaled
        const float bv = bias[h * 768 + colg] * bscale;
        const int d = colg - cb;
#pragma unroll
        for (int mf = 0; mf < 4; ++mf)
#pragma unroll
          for (int r = 0; r < 4; ++r) {
            const int mr = mbase + mf * 16 + lg * 4 + r;
            const int b = mr >> 11, s = mr & 2047;
            dst[((size_t)(b * 4 + h) * 2048 + s) * 256 + d] = f2bf(acc[mf][nf][r] + bv);
          }
      }
    } else {                                     // V (ny 4,5): transpose via LDS
      __syncthreads();
      short* tr = reinterpret_cast<short*>(smem);
#pragma unroll
      for (int nf = 0; nf < 4; ++nf) {
        const int colg = nbase + nf * 16 + l15;
        const float bv = bias[h * 768 + colg];
        const int cl = wc * 64 + nf * 16 + l15;
#pragma unroll
        for (int mf = 0; mf < 4; ++mf)
#pragma unroll
          for (int r = 0; r < 4; ++r) {
            const int rl = wr * 64 + mf * 16 + lg * 4 + r;
            tr[rl * 137 + cl] = (short)f2bf(acc[mf][nf][r] + bv);
          }
      }
      __syncthreads();
      const int b = bx >> 4;
#pragma unroll
      for (int rep = 0; rep < 8; ++rep) {
        const int u = rep * 256 + tid;
        const int d = u >> 4, sb = u & 15;       // d: local col 0..127, sb: 8-run idx
        const int dglob = (ny - 4) * 128 + d;
        const int tile = (bx & 15) * 2 + (sb >> 3);
        const int c = sb & 7;                    // kv chunk within 64-tile
        // phi^-1: kv run c*8..c*8+3 -> slot kA..kA+3 ; c*8+4..7 -> kA+8..+11
        const int kA = 32 * (c >> 2) + 8 * ((2 * c) & 3) + 4 * ((c >> 1) & 1);
        u16* base = Vo + (((size_t)(b * 4 + h) * 32 + tile) * 256 + dglob) * 64;
        ushort4 lo, hi;
        lo.x = (u16)tr[(sb * 8 + 0) * 137 + d];
        lo.y = (u16)tr[(sb * 8 + 1) * 137 + d];
        lo.z = (u16)tr[(sb * 8 + 2) * 137 + d];
        lo.w = (u16)tr[(sb * 8 + 3) * 137 + d];
        hi.x = (u16)tr[(sb * 8 + 4) * 137 + d];
        hi.y = (u16)tr[(sb * 8 + 5) * 137 + d];
        hi.z = (u16)tr[(sb * 8 + 6) * 137 + d];
        hi.w = (u16)tr[(sb * 8 + 7) * 137 + d];
        *reinterpret_cast<ushort4*>(base + kA)     = lo;
        *reinterpret_cast<ushort4*>(base + kA + 8) = hi;
      }
    }
  }
}

// ---------------------------------------------------------------------------
// Flash attention v6. Grid (32, 32): qt, bh. 4 waves x 16 q-rows, KVBLK=64,
// single-buffer 2-barrier loop. Swapped QK^T: Sx = mfma(K, Q) -> lane owns
// q-row (l&15), kv = 16nf+4lg+r in regs. In-lane softmax + 2 shuffles.
// P packed in-register (cvt_pk) straight into PV A-frags; phi baked into V.
// LDS: K 32K + V 32K = 64KB -> 2 blocks/CU, 8 waves/CU (the proven regime).
// ---------------------------------------------------------------------------
__global__ void __launch_bounds__(256, 2) attn_fwd(
    const u16* __restrict__ Q, const u16* __restrict__ Kk,
    const u16* __restrict__ Vt, u16* __restrict__ AO)
{
  const int qt = blockIdx.x;                     // 0..31
  const int bh = blockIdx.y;                     // 0..31
  const int tid = threadIdx.x;
  const int wid = tid >> 6, l = tid & 63;
  const int l15 = l & 15, lg = l >> 4;

  __shared__ __align__(16) char smem[65536];
  char* Kl = smem;
  char* Vl = smem + 32768;

  const size_t kbase = (size_t)bh * 2048 * 256;

  // Q fragments: 16 rows/wave (pre-scaled by log2e/16 upstream)
  s8v qa[8];
  {
    const u16* qrow = Q + ((size_t)bh * 2048 + qt * 64 + wid * 16 + l15) * 256;
#pragma unroll
    for (int kf = 0; kf < 8; ++kf)
      qa[kf] = *reinterpret_cast<const s8v*>(qrow + kf * 32 + lg * 8);
  }

  f4v O[16];
#pragma unroll
  for (int df = 0; df < 16; ++df) O[df] = f4v{0.f, 0.f, 0.f, 0.f};
  float m_run = -1e30f, l_run = 0.f;             // per-lane state for q = l15

  for (int t0 = 0; t0 < 2048; t0 += 64) {
    __syncthreads();                              // prev tile's LDS reads done
#pragma unroll
    for (int ii = 0; ii < 8; ++ii) {              // K tile 64x256 (rows 512B)
      const int i = wid * 8 + ii;
      const int row = i * 2 + (l >> 5);
      const int c = l & 31;
      gload16(Kk + kbase + (size_t)(t0 + row) * 256 + ((c ^ (row & 7)) << 3), Kl + i * 1024);
    }
    {
      const u16* vtile = Vt + ((size_t)bh * 32 + (t0 >> 6)) * 16384;  // [256][64]
#pragma unroll
      for (int ii = 0; ii < 8; ++ii) {            // V tile (contiguous 32KB)
        const int i = wid * 8 + ii;
        const int d = i * 8 + (l >> 3);
        const int c = l & 7;
        gload16(vtile + (size_t)d * 64 + ((c ^ (d & 7)) << 3), Vl + i * 1024);
      }
    }
    __syncthreads();                              // staged tile visible

    // QK^T swapped: Sx[nf] reg r = S[kv = nf*16 + lg*4 + r][q = l15]
    f4v Sx[4];
#pragma unroll
    for (int nf = 0; nf < 4; ++nf) Sx[nf] = f4v{0.f, 0.f, 0.f, 0.f};
#pragma unroll
    for (int kf = 0; kf < 8; ++kf) {
      const int ch = kf * 4 + lg;
#pragma unroll
      for (int nf = 0; nf < 4; ++nf) {
        const int tl = nf * 16 + l15;
        const s8v kb = *reinterpret_cast<const s8v*>(
            Kl + tl * 512 + ((ch ^ (tl & 7)) << 4));
        Sx[nf] = __builtin_amdgcn_mfma_f32_16x16x32_bf16(kb, qa[kf], Sx[nf], 0, 0, 0);
      }
    }

    // in-lane softmax for q = l15 (replicated across 4 lg groups)
    float mloc = fmaxf(fmaxf(fmaxf(Sx[0][0], Sx[0][1]), fmaxf(Sx[0][2], Sx[0][3])),
                       fmaxf(fmaxf(Sx[1][0], Sx[1][1]), fmaxf(Sx[1][2], Sx[1][3])));
    mloc = fmaxf(mloc, fmaxf(fmaxf(Sx[2][0], Sx[2][1]), fmaxf(Sx[2][2], Sx[2][3])));
    mloc = fmaxf(mloc, fmaxf(fmaxf(Sx[3][0], Sx[3][1]), fmaxf(Sx[3][2], Sx[3][3])));
    mloc = fmaxf(mloc, __shfl_xor(mloc, 16));
    mloc = fmaxf(mloc, __shfl_xor(mloc, 32));

    if (__any(mloc > m_run + 11.5f)) {            // defer-max (exp2 domain)
      const float mn = fmaxf(m_run, mloc);
      const float fac = __builtin_exp2f(m_run - mn);
      m_run = mn;
      l_run *= fac;
      float facr[4];
#pragma unroll
      for (int r = 0; r < 4; ++r) facr[r] = __shfl(fac, lg * 4 + r);  // fac of q=lg*4+r
#pragma unroll
      for (int df = 0; df < 16; ++df) {
        O[df][0] *= facr[0]; O[df][1] *= facr[1];
        O[df][2] *= facr[2]; O[df][3] *= facr[3];
      }
    }

    float p[4][4];
    float sum = 0.f;
#pragma unroll
    for (int nf = 0; nf < 4; ++nf)
#pragma unroll
      for (int r = 0; r < 4; ++r) {
        p[nf][r] = __builtin_exp2f(Sx[nf][r] - m_run);
        sum += p[nf][r];
      }
    sum += __shfl_xor(sum, 16);
    sum += __shfl_xor(sum, 32);
    l_run += sum;

    // pack P -> PV A-frags (phi layout: j0..3 <- p[2k][0..3], j4..7 <- p[2k+1][0..3])
    s8v pa[2];
#pragma unroll
    for (int kf2 = 0; kf2 < 2; ++kf2) {
      int4 w;
      w.x = (int)cvtpk(p[2 * kf2][0],     p[2 * kf2][1]);
      w.y = (int)cvtpk(p[2 * kf2][2],     p[2 * kf2][3]);
      w.z = (int)cvtpk(p[2 * kf2 + 1][0], p[2 * kf2 + 1][1]);
      w.w = (int)cvtpk(p[2 * kf2 + 1][2], p[2 * kf2 + 1][3]);
      pa[kf2] = __builtin_bit_cast(s8v, w);
    }

    // PV: O[q = lg*4+r][d]; V LDS slots already phi-permuted
#pragma unroll
    for (int kf2 = 0; kf2 < 2; ++kf2) {
      const int ch = kf2 * 4 + lg;
#pragma unroll
      for (int df = 0; df < 16; ++df) {
        const int dl = df * 16 + l15;
        const s8v vb = *reinterpret_cast<const s8v*>(
            Vl + dl * 128 + ((ch ^ (dl & 7)) << 4));
        O[df] = __builtin_amdgcn_mfma_f32_16x16x32_bf16(pa[kf2], vb, O[df], 0, 0, 0);
      }
    }
  }

  const float inv = 1.0f / l_run;                // for q = l15
  float invr[4];
#pragma unroll
  for (int r = 0; r < 4; ++r) invr[r] = __shfl(inv, lg * 4 + r);
  const int b = bh >> 2, h = bh & 3;
#pragma unroll
  for (int df = 0; df < 16; ++df)
#pragma unroll
    for (int r = 0; r < 4; ++r) {
      const int srow = qt * 64 + wid * 16 + lg * 4 + r;
      AO[(size_t)(b * 2048 + srow) * 1024 + h * 256 + df * 16 + l15] =
          f2bf(O[df][r] * invr[r]);
    }
}

// ---------------------------------------------------------------------------
extern "C" void kernel_launch(void* const* d_in, const int* in_sizes, int n_in,
                              void* d_out, int out_size, void* d_ws, size_t ws_size,
                              hipStream_t stream) {
  (void)in_sizes; (void)n_in; (void)out_size; (void)ws_size;
  const float* x     = (const float*)d_in[0];
  const float* W_lin = (const float*)d_in[1];
  const float* b_lin = (const float*)d_in[2];
  const float* W_in  = (const float*)d_in[3];
  const float* b_in  = (const float*)d_in[4];
  const float* W_out = (const float*)d_in[5];
  const float* b_out = (const float*)d_in[6];

  char* ws = (char*)d_ws;
  u16* Qb  = (u16*)(ws);                               // 32 MB [B,H,S,D]
  u16* Vtb = (u16*)(ws + (32ull << 20));               // 32 MB [B,H,32,256,64] tiled
  u16* AOb = (u16*)(ws + (64ull << 20));               // 32 MB [B,S,E]
  u16* WLb = (u16*)(ws + (96ull << 20));               // 2 MB
  u16* WIb = (u16*)(ws + (98ull << 20));               // 1.5 MB
  u16* WOb = (u16*)(ws + (98ull << 20) + 1572864ull);  // 0.5 MB

  char* doc  = (char*)d_out;
  u16* xb    = (u16*)doc;                    // 32 MB, dead after gemm<0>
  u16* xproj = (u16*)(doc + (32ull << 20));  // 32 MB, dead after gemm<1>
  u16* Kb    = (u16*)doc;                    // K reuses xb region [B,H,S,D]
  float* outF = (float*)d_out;

  cast_all<<<18432, 256, 0, stream>>>(x, W_lin, W_in, W_out, xb, WLb, WIb, WOb);

  gemm128<0><<<dim3(128, 8, 1), 256, 0, stream>>>(xb, WLb, b_lin, xproj, nullptr,
                                                  nullptr, nullptr, nullptr);
  gemm128<1><<<dim3(128, 6, 4), 256, 0, stream>>>(xproj, WIb, b_in, nullptr, nullptr,
                                                  Qb, Kb, Vtb);
  attn_fwd<<<dim3(32, 32, 1), 256, 0, stream>>>(Qb, Kb, Vtb, AOb);
  gemm128<2><<<dim3(128, 2, 4), 256, 0, stream>>>(AOb, WOb, b_out, nullptr, outF,
                                                  nullptr, nullptr, nullptr);
}